// Round 3
// baseline (110.651 us; speedup 1.0000x reference)
//
#include <hip/hip_runtime.h>

// CRF log-likelihood: mean_b( logZ_b - seq_score_b );  B=16, T=2048, K=16.
// Log-semiring matrix chain, 2 kernels:
//   stage1: B*NC blocks; product of CL consecutive KxK transfer matrices.
//           Row i owned by a 16-lane subgroup, broadcast via __shfl(width=16),
//           no LDS/barriers. Also computes per-chunk tag-seq score partials
//           and zeroes the completion counter for stage2.
//   stage2: B*8 blocks; folds 8 chunk matrices each. Last-arriving block
//           (device-scope fence + atomic counter) runs the finale: per-batch
//           row-0 vector chain over the 8 group matrices, logsumexp with
//           end_transitions, subtract seq score, mean over batches.
#define BB 16
#define TT 2048
#define KK 16
#define NC 64
#define CL 32   // TT / NC

__global__ __launch_bounds__(256) void crf_stage1(
    const float* __restrict__ em, const int* __restrict__ tags,
    const float* __restrict__ trans, const float* __restrict__ startT,
    const float* __restrict__ endT, float* __restrict__ chunkT,
    float* __restrict__ seqp, int* __restrict__ ctr)
{
    int blk = blockIdx.x;
    int b = blk >> 6;          // / NC
    int c = blk & (NC - 1);    // % NC
    int tid = threadIdx.x;
    int i = tid >> 4, k = tid & 15;

    if (blk == 0 && tid == 0) *ctr = 0;   // visible to stage2 via kernel boundary

    float tcol[KK];            // column k of transitions
#pragma unroll
    for (int j = 0; j < KK; ++j) tcol[j] = trans[j * KK + k];

    const float* emB = em + ((size_t)b * TT + c * CL) * KK;

    float cur = (c == 0 ? startT[k] : trans[i * KK + k]) + emB[k];

    float e_next = emB[KK + k];
#pragma unroll 4
    for (int t = 1; t < CL; ++t) {
        float e = e_next;
        if (t + 1 < CL) e_next = emB[(t + 1) * KK + k];
        float a[KK];
#pragma unroll
        for (int j = 0; j < KK; ++j)
            a[j] = __shfl(cur, j, 16) + tcol[j];   // row i broadcast, no barrier
        float m = a[0];
#pragma unroll
        for (int j = 1; j < KK; ++j) m = fmaxf(m, a[j]);
        float s = 0.f;
#pragma unroll
        for (int j = 0; j < KK; ++j) s += __expf(a[j] - m);
        cur = m + __logf(s) + e;
    }
    // transposed: chunkT[blk][k][i] so stage2 reads columns contiguously
    chunkT[(size_t)blk * 256 + k * KK + i] = cur;

    // ---- tag-seq score partial for t in [c*CL, c*CL+CL), one t per lane 0..31
    if (tid < 32) {
        int t = c * CL + tid;
        const int* tg = tags + (size_t)b * TT;
        int cu = tg[t];
        float part = em[((size_t)b * TT + t) * KK + cu];
        if (t + 1 < TT) part += trans[cu * KK + tg[t + 1]];
        if (t == 0) part += startT[cu];
        if (t == TT - 1) part += endT[cu];
#pragma unroll
        for (int off = 16; off; off >>= 1) part += __shfl_xor(part, off, 32);
        if (tid == 0) seqp[blk] = part;
    }
}

__global__ __launch_bounds__(256) void crf_stage2(
    const float* __restrict__ chunkT, const float* __restrict__ endT,
    const float* __restrict__ seqp, float* __restrict__ out2T,
    int* __restrict__ ctr, float* __restrict__ out)
{
    int blk = blockIdx.x;        // 128 blocks
    int b = blk >> 3;            // batch
    int g = blk & 7;             // group of 8 chunks
    int tid = threadIdx.x;
    int i = tid >> 4, k = tid & 15;

    const float* base = chunkT + ((size_t)(b * NC + g * 8)) * 256;
    float cur = base[k * KK + i];            // C_{g*8}[i][k]

#pragma unroll
    for (int c = 1; c < 8; ++c) {
        const float* mp = base + c * 256 + k * KK;   // column k, contiguous
        float mc[KK];
#pragma unroll
        for (int j = 0; j < KK; ++j) mc[j] = mp[j];
        float a[KK];
#pragma unroll
        for (int j = 0; j < KK; ++j)
            a[j] = __shfl(cur, j, 16) + mc[j];
        float m = a[0];
#pragma unroll
        for (int j = 1; j < KK; ++j) m = fmaxf(m, a[j]);
        float s = 0.f;
#pragma unroll
        for (int j = 0; j < KK; ++j) s += __expf(a[j] - m);
        cur = m + __logf(s);
    }
    out2T[(size_t)blk * 256 + k * KK + i] = cur;

    // ---- last-block-arrives finale
    __shared__ int lastFlag;
    __threadfence();                          // release our out2T writes
    if (tid == 0) {
        int old = atomicAdd(ctr, 1);          // device-scope
        lastFlag = (old == (BB * 8 - 1));
    }
    __syncthreads();
    if (!lastFlag) return;
    __threadfence();                          // acquire others' out2T writes

    int fb = tid >> 4;                        // batch, 16 groups x 16 lanes
    int fk = tid & 15;
    const float* fbase = out2T + (size_t)fb * 8 * 256;
    float v = fbase[fk * KK + 0];             // row 0 of G_0 (transposed storage)
#pragma unroll
    for (int g2 = 1; g2 < 8; ++g2) {
        const float* mp = fbase + g2 * 256 + fk * KK;
        float mc[KK];
#pragma unroll
        for (int j = 0; j < KK; ++j) mc[j] = mp[j];
        float a[KK];
#pragma unroll
        for (int j = 0; j < KK; ++j)
            a[j] = __shfl(v, j, 16) + mc[j];
        float m = a[0];
#pragma unroll
        for (int j = 1; j < KK; ++j) m = fmaxf(m, a[j]);
        float s = 0.f;
#pragma unroll
        for (int j = 0; j < KK; ++j) s += __expf(a[j] - m);
        v = m + __logf(s);
    }
    float fv = v + endT[fk];
    float m = fv;
#pragma unroll
    for (int off = 8; off; off >>= 1) m = fmaxf(m, __shfl_xor(m, off, 16));
    float s = __expf(fv - m);
#pragma unroll
    for (int off = 8; off; off >>= 1) s += __shfl_xor(s, off, 16);
    float logZ = m + __logf(s);               // uniform within 16-group

    // seq score: 64 chunk partials per batch
    float sq = seqp[fb * NC + fk] + seqp[fb * NC + fk + 16]
             + seqp[fb * NC + fk + 32] + seqp[fb * NC + fk + 48];
#pragma unroll
    for (int off = 8; off; off >>= 1) sq += __shfl_xor(sq, off, 16);

    __shared__ float red[BB];
    if (fk == 0) red[fb] = logZ - sq;
    __syncthreads();
    if (tid == 0) {
        float acc = 0.f;
#pragma unroll
        for (int bb = 0; bb < BB; ++bb) acc += red[bb];
        out[0] = acc * (1.f / BB);
    }
}

extern "C" void kernel_launch(void* const* d_in, const int* in_sizes, int n_in,
                              void* d_out, int out_size, void* d_ws, size_t ws_size,
                              hipStream_t stream)
{
    const float* em     = (const float*)d_in[0];
    const int*   tags   = (const int*)d_in[1];
    const float* trans  = (const float*)d_in[2];
    const float* startT = (const float*)d_in[3];
    const float* endT   = (const float*)d_in[4];
    float* out = (float*)d_out;

    float* chunkT = (float*)d_ws;                          // 16*64*256 f = 1 MiB
    float* out2T  = chunkT + (size_t)BB * NC * 256;        // 128*256 f
    float* seqp   = out2T + 128 * 256;                     // 1024 f
    int*   ctr    = (int*)(seqp + BB * NC);                // 1 int

    crf_stage1<<<BB * NC, 256, 0, stream>>>(em, tags, trans, startT, endT,
                                            chunkT, seqp, ctr);
    crf_stage2<<<BB * 8, 256, 0, stream>>>(chunkT, endT, seqp, out2T, ctr, out);
}

// Round 10
// 99.832 us; speedup vs baseline: 1.1084x; 1.1084x over previous
//
#include <hip/hip_runtime.h>

// CRF log-likelihood: mean_b( logZ_b - seq_score_b );  B=16, T=2048, K=16.
//
// Two launches:
//  s1 (1024 blocks x 256): round-2-proven log-domain shuffle/lse chain over
//     each chunk of CL=32 transfer matrices; then block-max normalize and
//     store the chunk matrix in the LINEAR domain: chunkE = exp(G - mx),
//     off1 = mx. Plain row-major => all loads/stores coalesced.
//  s2 (16 blocks x 512, one per batch): chunk folding is now ORDINARY f32
//     matmul NEW = ACC * F (no exp/log per term). Wave w folds its 8 chunks
//     (7 sequential folds; F prefetched into registers; ACC rows broadcast
//     from per-wave LDS; per-fold max-renorm + log offset). 3-level tree
//     combine across the 8 waves, then finale: logZ = log(row0 . exp(end))
//     + accumulated offsets. Seq score gathered by all 8 waves. One
//     atomicAdd per batch into out (zeroed by s1 block 0; kernel-boundary
//     ordering, no fences).
#define BB 16
#define TT 2048
#define KK 16
#define NC 64
#define CL 32   // TT / NC
#define WVS 8   // waves per s2 block
#define CPW 8   // chunks per wave = NC / WVS

__global__ __launch_bounds__(256) void crf_s1(
    const float* __restrict__ em, const float* __restrict__ trans,
    const float* __restrict__ startT, float* __restrict__ chunkE,
    float* __restrict__ off1, float* __restrict__ out)
{
    int blk = blockIdx.x;                  // 1024 = BB*NC
    int b = blk >> 6, c = blk & (NC - 1);
    int tid = threadIdx.x;
    int i = tid >> 4, k = tid & 15;
    if (blk == 0 && tid == 0) out[0] = 0.f;   // for s2's atomicAdd

    float tcol[KK];                        // column k of transitions
#pragma unroll
    for (int j = 0; j < KK; ++j) tcol[j] = trans[j * KK + k];

    const float* emB = em + ((size_t)(b * TT + c * CL)) * KK;
    float cur = (c == 0 ? startT[k] : trans[i * KK + k]) + emB[k];

    float e_next = emB[KK + k];
#pragma unroll 4
    for (int t = 1; t < CL; ++t) {
        float e = e_next;
        if (t + 1 < CL) e_next = emB[(t + 1) * KK + k];
        float a[KK];
        float m = -1e30f;
#pragma unroll
        for (int j = 0; j < KK; ++j) {
            a[j] = __shfl(cur, j, 16) + tcol[j];   // row i broadcast, no barrier
            m = fmaxf(m, a[j]);
        }
        float s = 0.f;
#pragma unroll
        for (int j = 0; j < KK; ++j) s += __expf(a[j] - m);
        cur = m + __logf(s) + e;
    }

    // block-wide max of the chunk's log-matrix
    float m = cur;
#pragma unroll
    for (int off = 32; off; off >>= 1) m = fmaxf(m, __shfl_xor(m, off));
    __shared__ float wmax[4];
    if ((tid & 63) == 0) wmax[tid >> 6] = m;
    __syncthreads();
    float mx = fmaxf(fmaxf(wmax[0], wmax[1]), fmaxf(wmax[2], wmax[3]));

    // linear-domain chunk matrix, plain row-major [i][k] (offset == tid)
    chunkE[(size_t)blk * 256 + tid] = __expf(cur - mx);
    if (tid == 0) off1[blk] = mx;
}

__global__ __launch_bounds__(512) void crf_s2(
    const float* __restrict__ chunkE, const float* __restrict__ off1,
    const float* __restrict__ em, const int* __restrict__ tags,
    const float* __restrict__ trans, const float* __restrict__ startT,
    const float* __restrict__ endT, float* __restrict__ out)
{
    int b = blockIdx.x;                    // 16 blocks, one per batch
    int tid = threadIdx.x;
    int w = tid >> 6, lane = tid & 63;
    int g = lane >> 4, li = lane & 15;     // row-group, column

    __shared__ float S[WVS][256];          // per-wave ACC, row-major [i*16+k]
    __shared__ float red[WVS];             // per-wave seq partials
    __shared__ float offw[WVS];            // per-wave log offsets

    // ---- tag-sequence score (all 8 waves, 4 tags per thread, coalesced)
    const int* tg = tags + (size_t)b * TT;
    float sq = 0.f;
#pragma unroll
    for (int s = 0; s < TT / 512; ++s) {
        int t = s * 512 + tid;
        int cu = tg[t];
        sq += em[((size_t)b * TT + t) * KK + cu];
        if (t + 1 < TT) sq += trans[cu * KK + tg[t + 1]];
        if (t == 0)      sq += startT[cu];
        if (t == TT - 1) sq += endT[cu];
    }
#pragma unroll
    for (int off = 32; off; off >>= 1) sq += __shfl_xor(sq, off);
    if (lane == 0) red[w] = sq;

    // ---- phase A: wave w folds chunks [c0, c0+CPW) -> S[w]
    int c0 = b * NC + w * CPW;
    float* Sw = S[w];
    const float* src0 = chunkE + (size_t)c0 * 256;
#pragma unroll
    for (int q = 0; q < 4; ++q)
        Sw[(4 * g + q) * 16 + li] = src0[(4 * g + q) * 16 + li];

    float offacc = (lane < CPW) ? off1[c0 + lane] : 0.f;
#pragma unroll
    for (int off = 32; off; off >>= 1) offacc += __shfl_xor(offacc, off);

    float fr[16], nf[16];                  // F column li, current + prefetch
#pragma unroll
    for (int kk = 0; kk < 16; ++kk) nf[kk] = src0[256 + kk * 16 + li];
    for (int c = 1; c < CPW; ++c) {
#pragma unroll
        for (int kk = 0; kk < 16; ++kk) fr[kk] = nf[kk];
        if (c + 1 < CPW) {
            const float* srcN = chunkE + (size_t)(c0 + c + 1) * 256;
#pragma unroll
            for (int kk = 0; kk < 16; ++kk) nf[kk] = srcN[kk * 16 + li];
        }
        float a0 = 0.f, a1 = 0.f, a2 = 0.f, a3 = 0.f;
#pragma unroll
        for (int kk = 0; kk < 16; ++kk) {
            float f = fr[kk];
            a0 = fmaf(Sw[(4 * g + 0) * 16 + kk], f, a0);   // LDS broadcast
            a1 = fmaf(Sw[(4 * g + 1) * 16 + kk], f, a1);
            a2 = fmaf(Sw[(4 * g + 2) * 16 + kk], f, a2);
            a3 = fmaf(Sw[(4 * g + 3) * 16 + kk], f, a3);
        }
        float m = fmaxf(fmaxf(a0, a1), fmaxf(a2, a3));
#pragma unroll
        for (int off = 32; off; off >>= 1) m = fmaxf(m, __shfl_xor(m, off));
        m = fmaxf(m, 1e-37f);
        float inv = __builtin_amdgcn_rcpf(m);
        offacc += __logf(m);
        Sw[(4 * g + 0) * 16 + li] = a0 * inv;   // reads above precede writes
        Sw[(4 * g + 1) * 16 + li] = a1 * inv;   // (same-wave DS in order)
        Sw[(4 * g + 2) * 16 + li] = a2 * inv;
        Sw[(4 * g + 3) * 16 + li] = a3 * inv;
    }
    if (lane == 0) offw[w] = offacc;
    __syncthreads();

    // ---- tree combine: ACC = A0*A1*...*A7 (X := X*Y each level)
    auto combine = [&](float* X, const float* Y, int xi, int yi) {
        float br[16];
#pragma unroll
        for (int kk = 0; kk < 16; ++kk) br[kk] = Y[kk * 16 + li];
        float a0 = 0.f, a1 = 0.f, a2 = 0.f, a3 = 0.f;
#pragma unroll
        for (int kk = 0; kk < 16; ++kk) {
            float f = br[kk];
            a0 = fmaf(X[(4 * g + 0) * 16 + kk], f, a0);
            a1 = fmaf(X[(4 * g + 1) * 16 + kk], f, a1);
            a2 = fmaf(X[(4 * g + 2) * 16 + kk], f, a2);
            a3 = fmaf(X[(4 * g + 3) * 16 + kk], f, a3);
        }
        float m = fmaxf(fmaxf(a0, a1), fmaxf(a2, a3));
#pragma unroll
        for (int off = 32; off; off >>= 1) m = fmaxf(m, __shfl_xor(m, off));
        m = fmaxf(m, 1e-37f);
        float inv = __builtin_amdgcn_rcpf(m);
        X[(4 * g + 0) * 16 + li] = a0 * inv;
        X[(4 * g + 1) * 16 + li] = a1 * inv;
        X[(4 * g + 2) * 16 + li] = a2 * inv;
        X[(4 * g + 3) * 16 + li] = a3 * inv;
        if (lane == 0) offw[xi] = offw[xi] + offw[yi] + __logf(m);
    };

    if (w < 4) combine(S[2 * w], S[2 * w + 1], 2 * w, 2 * w + 1);
    __syncthreads();
    if (w < 2) combine(S[4 * w], S[4 * w + 2], 4 * w, 4 * w + 2);
    __syncthreads();
    if (w == 0) {
        combine(S[0], S[4], 0, 4);
        // ---- finale: logZ = log( sum_j ACC[0][j]*exp(end[j]) ) + OFF
        float v = (lane < 16) ? S[0][lane] * __expf(endT[lane]) : 0.f;
#pragma unroll
        for (int off = 32; off; off >>= 1) v += __shfl_xor(v, off);
        if (lane == 0) {
            float seq = red[0] + red[1] + red[2] + red[3]
                      + red[4] + red[5] + red[6] + red[7];
            float logZ = __logf(v) + offw[0];
            atomicAdd(out, (logZ - seq) * (1.f / BB));
        }
    }
}

extern "C" void kernel_launch(void* const* d_in, const int* in_sizes, int n_in,
                              void* d_out, int out_size, void* d_ws, size_t ws_size,
                              hipStream_t stream)
{
    const float* em     = (const float*)d_in[0];
    const int*   tags   = (const int*)d_in[1];
    const float* trans  = (const float*)d_in[2];
    const float* startT = (const float*)d_in[3];
    const float* endT   = (const float*)d_in[4];
    float* out = (float*)d_out;

    float* chunkE = (float*)d_ws;                       // 1024*256*4B = 1 MiB
    float* off1   = chunkE + (size_t)BB * NC * 256;     // 4 KiB

    crf_s1<<<BB * NC, 256, 0, stream>>>(em, trans, startT, chunkE, off1, out);
    crf_s2<<<BB, 512, 0, stream>>>(chunkE, off1, em, tags, trans,
                                   startT, endT, out);
}